// Round 1
// baseline (1009.833 us; speedup 1.0000x reference)
//
#include <hip/hip_runtime.h>

constexpr float kEps = 1e-5f;

// ---------------- setup kernels ----------------

__global__ void zero_int2(int* __restrict__ a, int* __restrict__ b, int n) {
  int i = blockIdx.x * blockDim.x + threadIdx.x;
  if (i < n) { a[i] = 0; b[i] = 0; }
}

__global__ void hist_kernel(const int* __restrict__ dst, int* __restrict__ deg, int E) {
  int e = blockIdx.x * blockDim.x + threadIdx.x;
  if (e < E) atomicAdd(&deg[dst[e]], 1);
}

__global__ void scan1_kernel(const int* __restrict__ deg, int* __restrict__ off,
                             int* __restrict__ part, int N) {
  __shared__ int sm[1024];
  int i = blockIdx.x * 1024 + threadIdx.x;
  int v = (i < N) ? deg[i] : 0;
  sm[threadIdx.x] = v;
  __syncthreads();
  for (int o = 1; o < 1024; o <<= 1) {
    int t = (threadIdx.x >= o) ? sm[threadIdx.x - o] : 0;
    __syncthreads();
    sm[threadIdx.x] += t;
    __syncthreads();
  }
  if (i < N) off[i] = sm[threadIdx.x] - v;   // exclusive
  if (threadIdx.x == 1023) part[blockIdx.x] = sm[1023];
}

__global__ void scan2_kernel(int* __restrict__ part, int* __restrict__ off, int nb, int N) {
  if (threadIdx.x == 0) {
    int run = 0;
    for (int b = 0; b < nb; b++) { int p = part[b]; part[b] = run; run += p; }
    off[N] = run;
  }
}

__global__ void scan3_kernel(int* __restrict__ off, const int* __restrict__ part, int N) {
  int i = blockIdx.x * 1024 + threadIdx.x;
  if (i < N) off[i] += part[blockIdx.x];
}

__global__ void fill_kernel(const int* __restrict__ dst, const int* __restrict__ off,
                            int* __restrict__ cnt, int* __restrict__ edges, int E) {
  int e = blockIdx.x * blockDim.x + threadIdx.x;
  if (e < E) {
    int d = dst[e];
    int slot = off[d] + atomicAdd(&cnt[d], 1);
    edges[slot] = e;
  }
}

// deterministic edge order within each node (insertion sort; avg degree ~16)
__global__ void sort_kernel(const int* __restrict__ off, int* __restrict__ edges, int N) {
  int n = blockIdx.x * blockDim.x + threadIdx.x;
  if (n >= N) return;
  int b = off[n], e = off[n + 1];
  for (int i = b + 1; i < e; i++) {
    int key = edges[i];
    int j = i - 1;
    while (j >= b && edges[j] > key) { edges[j + 1] = edges[j]; j--; }
    edges[j + 1] = key;
  }
}

__global__ void adl_kernel(const int* __restrict__ deg, float* __restrict__ adl, int N) {
  __shared__ float sm[1024];
  float s = 0.f;
  for (int n = threadIdx.x; n < N; n += 1024) s += logf((float)deg[n] + 1.f);
  sm[threadIdx.x] = s;
  __syncthreads();
  for (int o = 512; o > 0; o >>= 1) {
    if (threadIdx.x < o) sm[threadIdx.x] += sm[threadIdx.x + o];
    __syncthreads();
  }
  if (threadIdx.x == 0) adl[0] = sm[0];   // sum of log(deg+1); consumers divide by N
}

// h0 = x @ node_W + node_b   (x: [N,128], W: [128,32])
__global__ void node_emb_kernel(const float* __restrict__ x, const float* __restrict__ W,
                                const float* __restrict__ b, float* __restrict__ h, int N) {
  int n = blockIdx.x * 8 + (threadIdx.x >> 5);
  int j = threadIdx.x & 31;
  if (n >= N) return;
  float acc = b[j];
  const float4* x4 = (const float4*)(x + (size_t)n * 128);
#pragma unroll
  for (int q = 0; q < 32; q++) {
    float4 v = x4[q];
    acc += v.x * W[(4 * q + 0) * 32 + j];
    acc += v.y * W[(4 * q + 1) * 32 + j];
    acc += v.z * W[(4 * q + 2) * 32 + j];
    acc += v.w * W[(4 * q + 3) * 32 + j];
  }
  h[n * 32 + j] = acc;
}

// Fold edge path: Wf[l,t] = (edge_W @ enc_W[l]) @ pre_W[l,t,64:96,:]  (16x32)
//                 bf[l,t] = ((edge_b@enc_W[l]+enc_b[l]) @ pre_W[l,t,64:96,:]) + pre_b[l,t]
__global__ void fuse_kernel(const float* __restrict__ edge_W, const float* __restrict__ edge_b,
                            const float* __restrict__ enc_W, const float* __restrict__ enc_b,
                            const float* __restrict__ pre_W, const float* __restrict__ pre_b,
                            float* __restrict__ Wf, float* __restrict__ bf) {
  __shared__ float tW[2][16][32];
  __shared__ float tb[2][32];
  int tid = threadIdx.x;
  for (int i = tid; i < 1024; i += 256) {
    int l = i >> 9, r = (i >> 5) & 15, c = i & 31;
    float s = 0.f;
    for (int k = 0; k < 32; k++) s += edge_W[r * 32 + k] * enc_W[(l * 32 + k) * 32 + c];
    tW[l][r][c] = s;
  }
  for (int i = tid; i < 64; i += 256) {
    int l = i >> 5, c = i & 31;
    float s = enc_b[l * 32 + c];
    for (int k = 0; k < 32; k++) s += edge_b[k] * enc_W[(l * 32 + k) * 32 + c];
    tb[l][c] = s;
  }
  __syncthreads();
  for (int i = tid; i < 4096; i += 256) {
    int l = i >> 11, t = (i >> 9) & 3, r = (i >> 5) & 15, c = i & 31;
    float s = 0.f;
    for (int k = 0; k < 32; k++) s += tW[l][r][k] * pre_W[((l * 4 + t) * 96 + 64 + k) * 32 + c];
    Wf[i] = s;
  }
  for (int i = tid; i < 256; i += 256) {
    int l = i >> 7, t = (i >> 5) & 3, c = i & 31;
    float s = pre_b[(l * 4 + t) * 32 + c];
    for (int k = 0; k < 32; k++) s += tb[l][k] * pre_W[((l * 4 + t) * 96 + 64 + k) * 32 + c];
    bf[i] = s;
  }
}

// ---------------- fused PNA layer ----------------
// 1 node per wave, 4 waves (256 thr) per block. Each lane owns 2 message
// components (t0,g) and (t0+2,g); edge loop keeps pre_nn weights in VGPRs.
// Stats -> LDS -> post_nn (post_W staged in LDS) -> lin -> out_pre.
__global__ __launch_bounds__(256) void layer_kernel(
    const float* __restrict__ h,
    const int* __restrict__ off, const int* __restrict__ edges,
    const int* __restrict__ src, const float* __restrict__ eattr,
    const float* __restrict__ ew, const int* __restrict__ deg,
    const float* __restrict__ adl,
    const float* __restrict__ preW,   // [4][96][32] (layer base)
    const float* __restrict__ Wf,     // [4][16][32]
    const float* __restrict__ bfv,    // [4][32]
    const float* __restrict__ postW,  // [4][416][8]
    const float* __restrict__ postB,  // [4][8]
    const float* __restrict__ linW,   // [32][32]
    const float* __restrict__ linB,   // [32]
    float* __restrict__ out_pre, int N) {
  __shared__ float pw[416 * 32];   // [f][t*8+g'] : 52 KB
  __shared__ float st[4][516];     // per-wave stats, tower stride 129 (pad)
  int tid = threadIdx.x;
  for (int i = tid; i < 13312; i += 256) {
    int t = i / 3328, r = i % 3328;
    int f = r >> 3, gq = r & 7;
    pw[f * 32 + t * 8 + gq] = postW[i];
  }
  __syncthreads();

  int wave = tid >> 6, lane = tid & 63;
  int n = blockIdx.x * 4 + wave;
  bool valid = (n < N);
  int t0 = lane >> 5, g = lane & 31;

  // per-lane pre_nn weights (src block + fused edge block) in registers
  float ws0[32], ws1[32], wf0[16], wf1[16];
  {
    const float* p0 = preW + (t0 * 96 + 32) * 32 + g;
    const float* p1 = preW + ((t0 + 2) * 96 + 32) * 32 + g;
#pragma unroll
    for (int f = 0; f < 32; f++) { ws0[f] = p0[f * 32]; ws1[f] = p1[f * 32]; }
    const float* q0 = Wf + (t0 * 16) * 32 + g;
    const float* q1 = Wf + ((t0 + 2) * 16) * 32 + g;
#pragma unroll
    for (int f = 0; f < 16; f++) { wf0[f] = q0[f * 32]; wf1[f] = q1[f * 32]; }
  }

  int dg = 0;
  if (valid) {
    dg = deg[n];
    // dst-block contribution + all fused biases (constant per node)
    float A0 = bfv[t0 * 32 + g];
    float A1 = bfv[(t0 + 2) * 32 + g];
    {
      const float4* h4 = (const float4*)(h + n * 32);
      const float* pA0 = preW + (t0 * 96) * 32 + g;
      const float* pA1 = preW + ((t0 + 2) * 96) * 32 + g;
#pragma unroll
      for (int qd = 0; qd < 8; qd++) {
        float4 hv = h4[qd];
        A0 += hv.x * pA0[(4 * qd + 0) * 32] + hv.y * pA0[(4 * qd + 1) * 32] +
              hv.z * pA0[(4 * qd + 2) * 32] + hv.w * pA0[(4 * qd + 3) * 32];
        A1 += hv.x * pA1[(4 * qd + 0) * 32] + hv.y * pA1[(4 * qd + 1) * 32] +
              hv.z * pA1[(4 * qd + 2) * 32] + hv.w * pA1[(4 * qd + 3) * 32];
      }
    }

    float s0 = 0.f, s1 = 0.f, sq0 = 0.f, sq1 = 0.f;
    float mn0 = 1e30f, mn1 = 1e30f, mx0 = -1e30f, mx1 = -1e30f;
    int beg = off[n], end = off[n + 1];
    int e = 0, sN = 0;
    float w = 0.f;
    if (beg < end) { e = edges[beg]; sN = src[e]; w = ew[e]; }
    for (int i = beg; i < end; i++) {
      int e_c = e, s_c = sN;
      float w_c = w;
      if (i + 1 < end) { e = edges[i + 1]; sN = src[e]; w = ew[e]; }  // prefetch indices
      const float4* hs = (const float4*)(h + s_c * 32);
      const float4* ea4 = (const float4*)(eattr + (size_t)e_c * 16);
      float v0 = A0, v1 = A1, u0 = 0.f, u1 = 0.f;
#pragma unroll
      for (int qd = 0; qd < 8; qd += 2) {
        float4 a = hs[qd], bq = hs[qd + 1];
        v0 += a.x * ws0[4 * qd + 0] + a.y * ws0[4 * qd + 1] + a.z * ws0[4 * qd + 2] + a.w * ws0[4 * qd + 3];
        v1 += a.x * ws1[4 * qd + 0] + a.y * ws1[4 * qd + 1] + a.z * ws1[4 * qd + 2] + a.w * ws1[4 * qd + 3];
        u0 += bq.x * ws0[4 * qd + 4] + bq.y * ws0[4 * qd + 5] + bq.z * ws0[4 * qd + 6] + bq.w * ws0[4 * qd + 7];
        u1 += bq.x * ws1[4 * qd + 4] + bq.y * ws1[4 * qd + 5] + bq.z * ws1[4 * qd + 6] + bq.w * ws1[4 * qd + 7];
      }
#pragma unroll
      for (int qd = 0; qd < 4; qd += 2) {
        float4 a = ea4[qd], bq = ea4[qd + 1];
        v0 += a.x * wf0[4 * qd + 0] + a.y * wf0[4 * qd + 1] + a.z * wf0[4 * qd + 2] + a.w * wf0[4 * qd + 3];
        v1 += a.x * wf1[4 * qd + 0] + a.y * wf1[4 * qd + 1] + a.z * wf1[4 * qd + 2] + a.w * wf1[4 * qd + 3];
        u0 += bq.x * wf0[4 * qd + 4] + bq.y * wf0[4 * qd + 5] + bq.z * wf0[4 * qd + 6] + bq.w * wf0[4 * qd + 7];
        u1 += bq.x * wf1[4 * qd + 4] + bq.y * wf1[4 * qd + 5] + bq.z * wf1[4 * qd + 6] + bq.w * wf1[4 * qd + 7];
      }
      v0 = (v0 + u0) * w_c;
      v1 = (v1 + u1) * w_c;
      s0 += v0; sq0 += v0 * v0; mn0 = fminf(mn0, v0); mx0 = fmaxf(mx0, v0);
      s1 += v1; sq1 += v1 * v1; mn1 = fminf(mn1, v1); mx1 = fmaxf(mx1, v1);
    }
    float degc = (float)(dg > 0 ? dg : 1);
    float inv = 1.f / degc;
    float mean0 = s0 * inv, mean1 = s1 * inv;
    float sd0 = sqrtf(fmaxf(sq0 * inv - mean0 * mean0, 0.f) + kEps);
    float sd1 = sqrtf(fmaxf(sq1 * inv - mean1 * mean1, 0.f) + kEps);
    if (dg == 0) { mn0 = 0.f; mx0 = 0.f; mn1 = 0.f; mx1 = 0.f; }
    float* sw = st[wave];
    sw[t0 * 129 + 0 * 32 + g] = mean0;
    sw[t0 * 129 + 1 * 32 + g] = mn0;
    sw[t0 * 129 + 2 * 32 + g] = mx0;
    sw[t0 * 129 + 3 * 32 + g] = sd0;
    sw[(t0 + 2) * 129 + 0 * 32 + g] = mean1;
    sw[(t0 + 2) * 129 + 1 * 32 + g] = mn1;
    sw[(t0 + 2) * 129 + 2 * 32 + g] = mx1;
    sw[(t0 + 2) * 129 + 3 * 32 + g] = sd1;
  }
  __syncthreads();
  if (!valid) return;  // no barriers below

  // post_nn + lin (all 64 lanes compute; lower 32 write)
  int c = lane & 31;
  int tP = c >> 3;
  float degc = (float)(dg > 0 ? dg : 1);
  float ad = adl[0] / (float)N;
  float ld = logf(degc + 1.f);
  float amp = ld / ad, att = ad / ld;
  float acc = postB[tP * 8 + (c & 7)];
  const float4* h4 = (const float4*)(h + n * 32);
#pragma unroll
  for (int qd = 0; qd < 8; qd++) {
    float4 hv = h4[qd];
    acc += hv.x * pw[(4 * qd + 0) * 32 + c] + hv.y * pw[(4 * qd + 1) * 32 + c] +
           hv.z * pw[(4 * qd + 2) * 32 + c] + hv.w * pw[(4 * qd + 3) * 32 + c];
  }
  const float* sw = st[wave] + tP * 129;
#pragma unroll 4
  for (int j = 0; j < 128; j++) {
    float sj = sw[j];
    float wgt = pw[(32 + j) * 32 + c] + amp * pw[(160 + j) * 32 + c] + att * pw[(288 + j) * 32 + c];
    acc += sj * wgt;
  }
  float o = linB[c];
#pragma unroll
  for (int k = 0; k < 32; k++) {
    float a = __shfl(acc, k);
    o += a * linW[k * 32 + c];
  }
  if (lane < 32) out_pre[n * 32 + lane] = o;
}

// ---------------- BN (deterministic) ----------------

__global__ void bn_stats_kernel(const float* __restrict__ pre, float* __restrict__ bn, int N) {
  int j = blockIdx.x;  // 32 columns
  __shared__ float ss[256], qq[256];
  float s = 0.f, q = 0.f;
  for (int n = threadIdx.x; n < N; n += 256) {
    float v = pre[n * 32 + j];
    s += v; q += v * v;
  }
  ss[threadIdx.x] = s; qq[threadIdx.x] = q;
  __syncthreads();
  for (int o = 128; o > 0; o >>= 1) {
    if (threadIdx.x < o) { ss[threadIdx.x] += ss[threadIdx.x + o]; qq[threadIdx.x] += qq[threadIdx.x + o]; }
    __syncthreads();
  }
  if (threadIdx.x == 0) { bn[j] = ss[0]; bn[32 + j] = qq[0]; }
}

__global__ void bn_apply_kernel(const float* __restrict__ pre, const float* __restrict__ bn,
                                const float* __restrict__ gamma, const float* __restrict__ beta,
                                float* __restrict__ h, int N) {
  int i = blockIdx.x * 256 + threadIdx.x;
  if (i >= N * 32) return;
  int j = i & 31;
  float invN = 1.f / (float)N;
  float mu = bn[j] * invN;
  float var = bn[32 + j] * invN - mu * mu;
  float is = rsqrtf(var + kEps);
  float v = (pre[i] - mu) * is * gamma[j] + beta[j];
  h[i] = fmaxf(v, 0.f);
}

// ---------------- pooling + MLP ----------------

__device__ __forceinline__ int lower_bound_dev(const int* a, int n, int key) {
  int lo = 0, hi = n;
  while (lo < hi) {
    int m = (lo + hi) >> 1;
    if (a[m] < key) lo = m + 1; else hi = m;
  }
  return lo;
}

__global__ void pool_kernel(const float* __restrict__ h, const int* __restrict__ batch,
                            float* __restrict__ gp, int N) {
  int gi = blockIdx.x;  // 64 graphs
  int lo = lower_bound_dev(batch, N, gi);
  int hi = lower_bound_dev(batch, N, gi + 1);
  __shared__ float part[8][32];
  int j = threadIdx.x & 31, ch = threadIdx.x >> 5;
  float s = 0.f;
  for (int n = lo + ch; n < hi; n += 8) s += h[n * 32 + j];
  part[ch][j] = s;
  __syncthreads();
  if (threadIdx.x < 32) {
    float t = 0.f;
    for (int c2 = 0; c2 < 8; c2++) t += part[c2][j];
    gp[gi * 32 + j] = t;
  }
}

__global__ void mlp_kernel(const float* __restrict__ gp,
                           const float* __restrict__ W1, const float* __restrict__ b1,
                           const float* __restrict__ W2, const float* __restrict__ b2,
                           const float* __restrict__ W3, const float* __restrict__ b3,
                           float* __restrict__ out) {
  __shared__ float g1[64 * 32];
  __shared__ float g2[64 * 16];
  int tid = threadIdx.x;  // 256
  for (int i = tid; i < 2048; i += 256) {
    int r = i >> 5, c = i & 31;
    float s = b1[c];
    for (int k = 0; k < 32; k++) s += gp[r * 32 + k] * W1[k * 32 + c];
    g1[i] = fmaxf(s, 0.f);
  }
  __syncthreads();
  for (int i = tid; i < 1024; i += 256) {
    int r = i >> 4, c = i & 15;
    float s = b2[c];
    for (int k = 0; k < 32; k++) s += g1[r * 32 + k] * W2[k * 16 + c];
    g2[i] = fmaxf(s, 0.f);
  }
  __syncthreads();
  if (tid < 64) {
    float s = b3[0];
    for (int k = 0; k < 16; k++) s += g2[tid * 16 + k] * W3[k];
    out[tid] = s;
  }
}

// ---------------- launch ----------------

extern "C" void kernel_launch(void* const* d_in, const int* in_sizes, int n_in,
                              void* d_out, int out_size, void* d_ws, size_t ws_size,
                              hipStream_t stream) {
  (void)n_in; (void)out_size; (void)ws_size;
  const float* x     = (const float*)d_in[0];
  const float* eattr = (const float*)d_in[1];
  const float* ew    = (const float*)d_in[2];
  const int*   eidx  = (const int*)d_in[3];
  const int*   batch = (const int*)d_in[4];
  const float* nodeW = (const float*)d_in[5];
  const float* nodeB = (const float*)d_in[6];
  const float* edgeW = (const float*)d_in[7];
  const float* edgeB = (const float*)d_in[8];
  const float* encW  = (const float*)d_in[9];
  const float* encB  = (const float*)d_in[10];
  const float* preW  = (const float*)d_in[11];
  const float* preB  = (const float*)d_in[12];
  const float* postW = (const float*)d_in[13];
  const float* postB = (const float*)d_in[14];
  const float* linW  = (const float*)d_in[15];
  const float* linB  = (const float*)d_in[16];
  const float* bnG   = (const float*)d_in[17];
  const float* bnB   = (const float*)d_in[18];
  const float* W1    = (const float*)d_in[19];
  const float* b1    = (const float*)d_in[20];
  const float* W2    = (const float*)d_in[21];
  const float* b2    = (const float*)d_in[22];
  const float* W3    = (const float*)d_in[23];
  const float* b3    = (const float*)d_in[24];
  float* out = (float*)d_out;

  int N = in_sizes[0] / 128;
  int E = in_sizes[2];
  const int* srcp = eidx;
  const int* dstp = eidx + E;

  char* wsb = (char*)d_ws;
  size_t woff = 0;
  auto alloc = [&](size_t bytes) -> void* {
    void* p = (void*)(wsb + woff);
    woff += (bytes + 255) & ~(size_t)255;
    return p;
  };
  int* deg  = (int*)alloc((size_t)N * 4);
  int* cnt  = (int*)alloc((size_t)N * 4);
  int* coff = (int*)alloc((size_t)(N + 1) * 4);
  int* part = (int*)alloc(64 * 4);
  int* edg  = (int*)alloc((size_t)E * 4);
  float* h    = (float*)alloc((size_t)N * 32 * 4);
  float* pre  = (float*)alloc((size_t)N * 32 * 4);
  float* adl  = (float*)alloc(256);
  float* bn   = (float*)alloc(64 * 4);
  float* gp   = (float*)alloc(64 * 32 * 4);
  float* WfB  = (float*)alloc(2 * 4 * 16 * 32 * 4);
  float* bfB  = (float*)alloc(2 * 4 * 32 * 4);

  int nb = (N + 1023) / 1024;
  zero_int2<<<(N + 255) / 256, 256, 0, stream>>>(deg, cnt, N);
  hist_kernel<<<(E + 255) / 256, 256, 0, stream>>>(dstp, deg, E);
  scan1_kernel<<<nb, 1024, 0, stream>>>(deg, coff, part, N);
  scan2_kernel<<<1, 64, 0, stream>>>(part, coff, nb, N);
  scan3_kernel<<<nb, 1024, 0, stream>>>(coff, part, N);
  fill_kernel<<<(E + 255) / 256, 256, 0, stream>>>(dstp, coff, cnt, edg, E);
  sort_kernel<<<(N + 255) / 256, 256, 0, stream>>>(coff, edg, N);
  adl_kernel<<<1, 1024, 0, stream>>>(deg, adl, N);
  node_emb_kernel<<<(N + 7) / 8, 256, 0, stream>>>(x, nodeW, nodeB, h, N);
  fuse_kernel<<<1, 256, 0, stream>>>(edgeW, edgeB, encW, encB, preW, preB, WfB, bfB);

  for (int l = 0; l < 2; l++) {
    layer_kernel<<<(N + 3) / 4, 256, 0, stream>>>(
        h, coff, edg, srcp, eattr, ew, deg, adl,
        preW + (size_t)l * 4 * 96 * 32, WfB + (size_t)l * 2048, bfB + (size_t)l * 128,
        postW + (size_t)l * 4 * 416 * 8, postB + (size_t)l * 32,
        linW + (size_t)l * 1024, linB + (size_t)l * 32,
        pre, N);
    bn_stats_kernel<<<32, 256, 0, stream>>>(pre, bn, N);
    bn_apply_kernel<<<(N * 32 + 255) / 256, 256, 0, stream>>>(pre, bn, bnG + (size_t)l * 32,
                                                              bnB + (size_t)l * 32, h, N);
  }
  pool_kernel<<<64, 256, 0, stream>>>(h, batch, gp, N);
  mlp_kernel<<<1, 256, 0, stream>>>(gp, W1, b1, W2, b2, W3, b3, out);
}

// Round 2
// 697.613 us; speedup vs baseline: 1.4476x; 1.4476x over previous
//
#include <hip/hip_runtime.h>

constexpr float kEps = 1e-5f;

__device__ __forceinline__ unsigned short f2bf(float x) {
  unsigned int u = __float_as_uint(x);
  unsigned int r = (u + 0x7fffu + ((u >> 16) & 1u)) >> 16;
  return (unsigned short)r;
}
__device__ __forceinline__ float bflo(unsigned int u) { return __uint_as_float(u << 16); }
__device__ __forceinline__ float bfhi(unsigned int u) { return __uint_as_float(u & 0xffff0000u); }
__device__ __forceinline__ unsigned int packbf(float a, float b) {
  return (unsigned int)f2bf(a) | ((unsigned int)f2bf(b) << 16);
}

// ---------------- setup kernels ----------------

__global__ void zero_int2(int* __restrict__ a, int* __restrict__ b, int n) {
  int i = blockIdx.x * blockDim.x + threadIdx.x;
  if (i < n) { a[i] = 0; b[i] = 0; }
}

__global__ void hist_kernel(const int* __restrict__ dst, int* __restrict__ deg, int E) {
  int e = blockIdx.x * blockDim.x + threadIdx.x;
  if (e < E) atomicAdd(&deg[dst[e]], 1);
}

__global__ void scan1_kernel(const int* __restrict__ deg, int* __restrict__ off,
                             int* __restrict__ part, int N) {
  __shared__ int sm[1024];
  int i = blockIdx.x * 1024 + threadIdx.x;
  int v = (i < N) ? deg[i] : 0;
  sm[threadIdx.x] = v;
  __syncthreads();
  for (int o = 1; o < 1024; o <<= 1) {
    int t = (threadIdx.x >= o) ? sm[threadIdx.x - o] : 0;
    __syncthreads();
    sm[threadIdx.x] += t;
    __syncthreads();
  }
  if (i < N) off[i] = sm[threadIdx.x] - v;   // exclusive
  if (threadIdx.x == 1023) part[blockIdx.x] = sm[1023];
}

__global__ void scan2_kernel(int* __restrict__ part, int* __restrict__ off, int nb, int N) {
  if (threadIdx.x == 0) {
    int run = 0;
    for (int b = 0; b < nb; b++) { int p = part[b]; part[b] = run; run += p; }
    off[N] = run;
  }
}

__global__ void scan3_kernel(int* __restrict__ off, const int* __restrict__ part, int N) {
  int i = blockIdx.x * 1024 + threadIdx.x;
  if (i < N) off[i] += part[blockIdx.x];
}

__global__ void fill_kernel(const int* __restrict__ dst, const int* __restrict__ off,
                            int* __restrict__ cnt, int* __restrict__ edges, int E) {
  int e = blockIdx.x * blockDim.x + threadIdx.x;
  if (e < E) {
    int d = dst[e];
    int slot = off[d] + atomicAdd(&cnt[d], 1);
    edges[slot] = e;
  }
}

// deterministic edge order within each node (insertion sort; avg degree ~16)
__global__ void sort_kernel(const int* __restrict__ off, int* __restrict__ edges, int N) {
  int n = blockIdx.x * blockDim.x + threadIdx.x;
  if (n >= N) return;
  int b = off[n], e = off[n + 1];
  for (int i = b + 1; i < e; i++) {
    int key = edges[i];
    int j = i - 1;
    while (j >= b && edges[j] > key) { edges[j + 1] = edges[j]; j--; }
    edges[j + 1] = key;
  }
}

// srcs[slot] = src[edg[slot]], ews[slot] = ew[edg[slot]]  (CSR-order copies)
__global__ void gather_kernel(const int* __restrict__ edg, const int* __restrict__ src,
                              const float* __restrict__ ew, int* __restrict__ srcs,
                              float* __restrict__ ews, int E) {
  int i = blockIdx.x * blockDim.x + threadIdx.x;
  if (i < E) {
    int e = edg[i];
    srcs[i] = src[e];
    ews[i] = ew[e];
  }
}

__global__ void adl_kernel(const int* __restrict__ deg, float* __restrict__ adl, int N) {
  __shared__ float sm[1024];
  float s = 0.f;
  for (int n = threadIdx.x; n < N; n += 1024) s += logf((float)deg[n] + 1.f);
  sm[threadIdx.x] = s;
  __syncthreads();
  for (int o = 512; o > 0; o >>= 1) {
    if (threadIdx.x < o) sm[threadIdx.x] += sm[threadIdx.x + o];
    __syncthreads();
  }
  if (threadIdx.x == 0) adl[0] = sm[0];   // sum of log(deg+1); consumers divide by N
}

// h0 = x @ node_W + node_b   (x: [N,128], W: [128,32])
__global__ void node_emb_kernel(const float* __restrict__ x, const float* __restrict__ W,
                                const float* __restrict__ b, float* __restrict__ h, int N) {
  int n = blockIdx.x * 8 + (threadIdx.x >> 5);
  int j = threadIdx.x & 31;
  if (n >= N) return;
  float acc = b[j];
  const float4* x4 = (const float4*)(x + (size_t)n * 128);
#pragma unroll
  for (int q = 0; q < 32; q++) {
    float4 v = x4[q];
    acc += v.x * W[(4 * q + 0) * 32 + j];
    acc += v.y * W[(4 * q + 1) * 32 + j];
    acc += v.z * W[(4 * q + 2) * 32 + j];
    acc += v.w * W[(4 * q + 3) * 32 + j];
  }
  h[n * 32 + j] = acc;
}

// Fold edge path: Wf[l,t] = (edge_W @ enc_W[l]) @ pre_W[l,t,64:96,:]  (16x32)
//                 bf[l,t] = ((edge_b@enc_W[l]+enc_b[l]) @ pre_W[l,t,64:96,:]) + pre_b[l,t]
__global__ void fuse_kernel(const float* __restrict__ edge_W, const float* __restrict__ edge_b,
                            const float* __restrict__ enc_W, const float* __restrict__ enc_b,
                            const float* __restrict__ pre_W, const float* __restrict__ pre_b,
                            float* __restrict__ Wf, float* __restrict__ bf) {
  __shared__ float tW[2][16][32];
  __shared__ float tb[2][32];
  int tid = threadIdx.x;
  for (int i = tid; i < 1024; i += 256) {
    int l = i >> 9, r = (i >> 5) & 15, c = i & 31;
    float s = 0.f;
    for (int k = 0; k < 32; k++) s += edge_W[r * 32 + k] * enc_W[(l * 32 + k) * 32 + c];
    tW[l][r][c] = s;
  }
  for (int i = tid; i < 64; i += 256) {
    int l = i >> 5, c = i & 31;
    float s = enc_b[l * 32 + c];
    for (int k = 0; k < 32; k++) s += edge_b[k] * enc_W[(l * 32 + k) * 32 + c];
    tb[l][c] = s;
  }
  __syncthreads();
  for (int i = tid; i < 4096; i += 256) {
    int l = i >> 11, t = (i >> 9) & 3, r = (i >> 5) & 15, c = i & 31;
    float s = 0.f;
    for (int k = 0; k < 32; k++) s += tW[l][r][k] * pre_W[((l * 4 + t) * 96 + 64 + k) * 32 + c];
    Wf[i] = s;
  }
  for (int i = tid; i < 256; i += 256) {
    int l = i >> 7, t = (i >> 5) & 3, c = i & 31;
    float s = pre_b[(l * 4 + t) * 32 + c];
    for (int k = 0; k < 32; k++) s += tb[l][k] * pre_W[((l * 4 + t) * 96 + 64 + k) * 32 + c];
    bf[i] = s;
  }
}

// ---------------- per-layer: node pre-projection ----------------
// q[n][c] = sum_k h[n][k] * preW[t][32+k][g]           (src block)
// A[n][c] = bfv[c] + sum_k h[n][k] * preW[t][k][g]     (dst block + fused bias)
// c = t*32+g, stored bf16.
__global__ __launch_bounds__(256) void prep_kernel(
    const float* __restrict__ h, const float* __restrict__ preW,
    const float* __restrict__ bfv, unsigned short* __restrict__ qB,
    unsigned short* __restrict__ AB, int N) {
  __shared__ float hs[16][32];
  int tid = threadIdx.x;
  int c = tid & 127, half = tid >> 7;
  int t = c >> 5, g = c & 31;
  float ws[32], wd[32];
  {
    const float* pS = preW + (t * 96 + 32) * 32 + g;
    const float* pD = preW + (t * 96) * 32 + g;
#pragma unroll
    for (int k = 0; k < 32; k++) { ws[k] = pS[k * 32]; wd[k] = pD[k * 32]; }
  }
  float bc = bfv[c];
  int base = blockIdx.x * 16;
  for (int i = tid; i < 512; i += 256) {
    int nn = i >> 5;
    hs[nn][i & 31] = (base + nn < N) ? h[(size_t)(base + nn) * 32 + (i & 31)] : 0.f;
  }
  __syncthreads();
#pragma unroll
  for (int nn = 0; nn < 8; ++nn) {
    int nl = half + 2 * nn;
    int n = base + nl;
    if (n >= N) continue;
    float qa = 0.f, Aa = bc;
#pragma unroll
    for (int k = 0; k < 32; k++) {
      float hk = hs[nl][k];
      qa = fmaf(hk, ws[k], qa);
      Aa = fmaf(hk, wd[k], Aa);
    }
    qB[(size_t)n * 128 + c] = f2bf(qa);
    AB[(size_t)n * 128 + c] = f2bf(Aa);
  }
}

// ---------------- per-layer: edge aggregation ----------------
// One node per wave; lane owns comps (2l, 2l+1). msg = (A[dst]+q[src]+eattr@Wf)*w.
// Stats (mean,min,max,std) kept in regs, written bf16 to stats[N][4][128].
__global__ __launch_bounds__(256) void agg_kernel(
    const unsigned int* __restrict__ qB,   // [N][64] packed bf16 pairs
    const unsigned int* __restrict__ AB,
    const int* __restrict__ coff, const int* __restrict__ srcs,
    const float* __restrict__ ews, const int* __restrict__ edg,
    const float* __restrict__ eattr, const float* __restrict__ Wf,
    unsigned int* __restrict__ stats,      // [N][4][64] packed bf16 pairs
    int N) {
  int tid = threadIdx.x;
  int wave = tid >> 6, lane = tid & 63;
  int n = blockIdx.x * 4 + wave;
  if (n >= N) return;
  int t = lane >> 4;            // tower of comp 2*lane
  int g0 = (2 * lane) & 31;
  float wfa[16], wfb[16];
  {
    const float* p = Wf + t * 16 * 32 + g0;
#pragma unroll
    for (int k = 0; k < 16; k++) { wfa[k] = p[k * 32]; wfb[k] = p[k * 32 + 1]; }
  }
  unsigned int au = AB[(size_t)n * 64 + lane];
  float a0 = bflo(au), a1 = bfhi(au);

  int beg = coff[n], end = coff[n + 1];
  int dg = end - beg;
  float s0 = 0.f, s1 = 0.f, sq0 = 0.f, sq1 = 0.f;
  float mn0 = 1e30f, mn1 = 1e30f, mx0 = -1e30f, mx1 = -1e30f;

  if (dg > 0) {
    int last = end - 1;
    // stage 0: indices+data for edge beg
    int sA = srcs[beg], eA = edg[beg];
    float wC = ews[beg];
    unsigned int quC = qB[(size_t)sA * 64 + lane];
    const float4* ea = (const float4*)(eattr + (size_t)eA * 16);
    float4 e0 = ea[0], e1 = ea[1], e2 = ea[2], e3 = ea[3];
    // indices for edge beg+1
    int i1 = min(beg + 1, last);
    int sB = srcs[i1], eB = edg[i1];
    float wB = ews[i1];
    for (int i = beg; i <= last; ++i) {
      // issue data prefetch for i+1
      unsigned int quN = qB[(size_t)sB * 64 + lane];
      const float4* ean = (const float4*)(eattr + (size_t)eB * 16);
      float4 n0 = ean[0], n1 = ean[1], n2 = ean[2], n3 = ean[3];
      float wN = wB;
      // issue index loads for i+2
      int i2 = min(i + 2, last);
      sB = srcs[i2]; eB = edg[i2]; wB = ews[i2];
      // compute edge i
      float ql = bflo(quC), qh = bfhi(quC);
      float f0, f1;
      f0 = e0.x * wfa[0];  f1 = e0.x * wfb[0];
      f0 = fmaf(e0.y, wfa[1], f0);  f1 = fmaf(e0.y, wfb[1], f1);
      f0 = fmaf(e0.z, wfa[2], f0);  f1 = fmaf(e0.z, wfb[2], f1);
      f0 = fmaf(e0.w, wfa[3], f0);  f1 = fmaf(e0.w, wfb[3], f1);
      f0 = fmaf(e1.x, wfa[4], f0);  f1 = fmaf(e1.x, wfb[4], f1);
      f0 = fmaf(e1.y, wfa[5], f0);  f1 = fmaf(e1.y, wfb[5], f1);
      f0 = fmaf(e1.z, wfa[6], f0);  f1 = fmaf(e1.z, wfb[6], f1);
      f0 = fmaf(e1.w, wfa[7], f0);  f1 = fmaf(e1.w, wfb[7], f1);
      f0 = fmaf(e2.x, wfa[8], f0);  f1 = fmaf(e2.x, wfb[8], f1);
      f0 = fmaf(e2.y, wfa[9], f0);  f1 = fmaf(e2.y, wfb[9], f1);
      f0 = fmaf(e2.z, wfa[10], f0); f1 = fmaf(e2.z, wfb[10], f1);
      f0 = fmaf(e2.w, wfa[11], f0); f1 = fmaf(e2.w, wfb[11], f1);
      f0 = fmaf(e3.x, wfa[12], f0); f1 = fmaf(e3.x, wfb[12], f1);
      f0 = fmaf(e3.y, wfa[13], f0); f1 = fmaf(e3.y, wfb[13], f1);
      f0 = fmaf(e3.z, wfa[14], f0); f1 = fmaf(e3.z, wfb[14], f1);
      f0 = fmaf(e3.w, wfa[15], f0); f1 = fmaf(e3.w, wfb[15], f1);
      float v0 = (a0 + ql + f0) * wC;
      float v1 = (a1 + qh + f1) * wC;
      s0 += v0; sq0 = fmaf(v0, v0, sq0); mn0 = fminf(mn0, v0); mx0 = fmaxf(mx0, v0);
      s1 += v1; sq1 = fmaf(v1, v1, sq1); mn1 = fminf(mn1, v1); mx1 = fmaxf(mx1, v1);
      // rotate
      quC = quN; e0 = n0; e1 = n1; e2 = n2; e3 = n3; wC = wN;
    }
  } else {
    mn0 = 0.f; mx0 = 0.f; mn1 = 0.f; mx1 = 0.f;
  }
  float inv = 1.f / (float)(dg > 0 ? dg : 1);
  float mean0 = s0 * inv, mean1 = s1 * inv;
  float sd0 = sqrtf(fmaxf(sq0 * inv - mean0 * mean0, 0.f) + kEps);
  float sd1 = sqrtf(fmaxf(sq1 * inv - mean1 * mean1, 0.f) + kEps);
  unsigned int* sp = stats + (size_t)n * 256;
  sp[0 * 64 + lane] = packbf(mean0, mean1);
  sp[1 * 64 + lane] = packbf(mn0, mn1);
  sp[2 * 64 + lane] = packbf(mx0, mx1);
  sp[3 * 64 + lane] = packbf(sd0, sd1);
}

// ---------------- per-layer: post_nn + lin ----------------
// Grid-stride over nodes; post_W staged once per block in LDS.
// Wave per node; lane = (c 0..31, hh 0..1) splits the 128-j loop in half.
__global__ __launch_bounds__(256) void post_kernel(
    const float* __restrict__ h, const unsigned int* __restrict__ stats,
    const int* __restrict__ coff, const float* __restrict__ adl,
    const float* __restrict__ postW, const float* __restrict__ postB,
    const float* __restrict__ linW, const float* __restrict__ linB,
    float* __restrict__ pre, int N) {
  __shared__ float pw[416 * 32];   // [f][t*8+q'] : 52 KB
  __shared__ float st4[4][576];    // per-wave stats, block b=s*4+tP stride 36
  int tid = threadIdx.x;
  for (int i = tid; i < 13312; i += 256) {
    int t = i / 3328, r = i % 3328;
    int f = r >> 3, gq = r & 7;
    pw[f * 32 + t * 8 + gq] = postW[i];
  }
  __syncthreads();

  int wave = tid >> 6, lane = tid & 63;
  int c = lane & 31, hh = lane >> 5;
  int tP = c >> 3;
  float adN = adl[0];
  float* stw = st4[wave];

  for (int n = blockIdx.x * 4 + wave; n < N; n += gridDim.x * 4) {
    // stage this node's stats (512 bf16) into LDS as f32, padded layout
    {
      uint4 su = ((const uint4*)stats)[(size_t)n * 64 + lane];
      int b = lane >> 2;                 // f>>5 with f=8*lane
      int gg = (lane & 3) * 8;
      float* w0 = &stw[b * 36 + gg];
      w0[0] = bflo(su.x); w0[1] = bfhi(su.x);
      w0[2] = bflo(su.y); w0[3] = bfhi(su.y);
      w0[4] = bflo(su.z); w0[5] = bfhi(su.z);
      w0[6] = bflo(su.w); w0[7] = bfhi(su.w);
    }
    int dg = coff[n + 1] - coff[n];
    float degc = (float)(dg > 0 ? dg : 1);
    float ad = adN / (float)N;
    float ld = logf(degc + 1.f);
    float amp = ld / ad, att = ad / ld;

    float acc = (hh == 0) ? postB[tP * 8 + (c & 7)] : 0.f;
    // h block (k split across halves)
    const float4* h4 = (const float4*)(h + (size_t)n * 32);
#pragma unroll
    for (int q4 = 0; q4 < 4; q4++) {
      float4 hv = h4[hh * 4 + q4];
      int k = hh * 16 + q4 * 4;
      acc = fmaf(hv.x, pw[(k + 0) * 32 + c], acc);
      acc = fmaf(hv.y, pw[(k + 1) * 32 + c], acc);
      acc = fmaf(hv.z, pw[(k + 2) * 32 + c], acc);
      acc = fmaf(hv.w, pw[(k + 3) * 32 + c], acc);
    }
    // agg block: j in [hh*64, hh*64+64)
#pragma unroll 4
    for (int jj = 0; jj < 64; jj++) {
      int j = hh * 64 + jj;
      float sj = stw[((j >> 5) * 4 + tP) * 36 + (j & 31)];
      float wgt = pw[(32 + j) * 32 + c];
      wgt = fmaf(amp, pw[(160 + j) * 32 + c], wgt);
      wgt = fmaf(att, pw[(288 + j) * 32 + c], wgt);
      acc = fmaf(sj, wgt, acc);
    }
    acc += __shfl_xor(acc, 32);
    // lin
    float o = linB[c];
#pragma unroll
    for (int k = 0; k < 32; k++) {
      float a = __shfl(acc, k);
      o = fmaf(a, linW[k * 32 + c], o);
    }
    if (lane < 32) pre[(size_t)n * 32 + c] = o;
  }
}

// ---------------- BN (deterministic) ----------------

__global__ void bn_stats_kernel(const float* __restrict__ pre, float* __restrict__ bn, int N) {
  int j = blockIdx.x;  // 32 columns
  __shared__ float ss[256], qq[256];
  float s = 0.f, q = 0.f;
  for (int n = threadIdx.x; n < N; n += 256) {
    float v = pre[(size_t)n * 32 + j];
    s += v; q += v * v;
  }
  ss[threadIdx.x] = s; qq[threadIdx.x] = q;
  __syncthreads();
  for (int o = 128; o > 0; o >>= 1) {
    if (threadIdx.x < o) { ss[threadIdx.x] += ss[threadIdx.x + o]; qq[threadIdx.x] += qq[threadIdx.x + o]; }
    __syncthreads();
  }
  if (threadIdx.x == 0) { bn[j] = ss[0]; bn[32 + j] = qq[0]; }
}

__global__ void bn_apply_kernel(const float* __restrict__ pre, const float* __restrict__ bn,
                                const float* __restrict__ gamma, const float* __restrict__ beta,
                                float* __restrict__ h, int N) {
  int i = blockIdx.x * 256 + threadIdx.x;
  if (i >= N * 32) return;
  int j = i & 31;
  float invN = 1.f / (float)N;
  float mu = bn[j] * invN;
  float var = bn[32 + j] * invN - mu * mu;
  float is = rsqrtf(var + kEps);
  float v = (pre[i] - mu) * is * gamma[j] + beta[j];
  h[i] = fmaxf(v, 0.f);
}

// ---------------- pooling + MLP ----------------

__device__ __forceinline__ int lower_bound_dev(const int* a, int n, int key) {
  int lo = 0, hi = n;
  while (lo < hi) {
    int m = (lo + hi) >> 1;
    if (a[m] < key) lo = m + 1; else hi = m;
  }
  return lo;
}

__global__ void pool_kernel(const float* __restrict__ h, const int* __restrict__ batch,
                            float* __restrict__ gp, int N) {
  int gi = blockIdx.x;  // 64 graphs
  int lo = lower_bound_dev(batch, N, gi);
  int hi = lower_bound_dev(batch, N, gi + 1);
  __shared__ float part[8][32];
  int j = threadIdx.x & 31, ch = threadIdx.x >> 5;
  float s = 0.f;
  for (int n = lo + ch; n < hi; n += 8) s += h[(size_t)n * 32 + j];
  part[ch][j] = s;
  __syncthreads();
  if (threadIdx.x < 32) {
    float t = 0.f;
    for (int c2 = 0; c2 < 8; c2++) t += part[c2][j];
    gp[gi * 32 + j] = t;
  }
}

__global__ void mlp_kernel(const float* __restrict__ gp,
                           const float* __restrict__ W1, const float* __restrict__ b1,
                           const float* __restrict__ W2, const float* __restrict__ b2,
                           const float* __restrict__ W3, const float* __restrict__ b3,
                           float* __restrict__ out) {
  __shared__ float g1[64 * 32];
  __shared__ float g2[64 * 16];
  int tid = threadIdx.x;  // 256
  for (int i = tid; i < 2048; i += 256) {
    int r = i >> 5, c = i & 31;
    float s = b1[c];
    for (int k = 0; k < 32; k++) s += gp[r * 32 + k] * W1[k * 32 + c];
    g1[i] = fmaxf(s, 0.f);
  }
  __syncthreads();
  for (int i = tid; i < 1024; i += 256) {
    int r = i >> 4, c = i & 15;
    float s = b2[c];
    for (int k = 0; k < 32; k++) s += g1[r * 32 + k] * W2[k * 16 + c];
    g2[i] = fmaxf(s, 0.f);
  }
  __syncthreads();
  if (tid < 64) {
    float s = b3[0];
    for (int k = 0; k < 16; k++) s += g2[tid * 16 + k] * W3[k];
    out[tid] = s;
  }
}

// ---------------- launch ----------------

extern "C" void kernel_launch(void* const* d_in, const int* in_sizes, int n_in,
                              void* d_out, int out_size, void* d_ws, size_t ws_size,
                              hipStream_t stream) {
  (void)n_in; (void)out_size; (void)ws_size;
  const float* x     = (const float*)d_in[0];
  const float* eattr = (const float*)d_in[1];
  const float* ew    = (const float*)d_in[2];
  const int*   eidx  = (const int*)d_in[3];
  const int*   batch = (const int*)d_in[4];
  const float* nodeW = (const float*)d_in[5];
  const float* nodeB = (const float*)d_in[6];
  const float* edgeW = (const float*)d_in[7];
  const float* edgeB = (const float*)d_in[8];
  const float* encW  = (const float*)d_in[9];
  const float* encB  = (const float*)d_in[10];
  const float* preW  = (const float*)d_in[11];
  const float* preB  = (const float*)d_in[12];
  const float* postW = (const float*)d_in[13];
  const float* postB = (const float*)d_in[14];
  const float* linW  = (const float*)d_in[15];
  const float* linB  = (const float*)d_in[16];
  const float* bnG   = (const float*)d_in[17];
  const float* bnB   = (const float*)d_in[18];
  const float* W1    = (const float*)d_in[19];
  const float* b1    = (const float*)d_in[20];
  const float* W2    = (const float*)d_in[21];
  const float* b2    = (const float*)d_in[22];
  const float* W3    = (const float*)d_in[23];
  const float* b3    = (const float*)d_in[24];
  float* out = (float*)d_out;

  int N = in_sizes[0] / 128;
  int E = in_sizes[2];
  const int* srcp = eidx;
  const int* dstp = eidx + E;

  char* wsb = (char*)d_ws;
  size_t woff = 0;
  auto alloc = [&](size_t bytes) -> void* {
    void* p = (void*)(wsb + woff);
    woff += (bytes + 255) & ~(size_t)255;
    return p;
  };
  int* deg   = (int*)alloc((size_t)N * 4);
  int* cnt   = (int*)alloc((size_t)N * 4);
  int* coff  = (int*)alloc((size_t)(N + 1) * 4);
  int* part  = (int*)alloc(64 * 4);
  int* edg   = (int*)alloc((size_t)E * 4);
  int* srcs  = (int*)alloc((size_t)E * 4);
  float* ews = (float*)alloc((size_t)E * 4);
  float* h    = (float*)alloc((size_t)N * 32 * 4);
  float* pre  = (float*)alloc((size_t)N * 32 * 4);
  float* adl  = (float*)alloc(256);
  float* bn   = (float*)alloc(64 * 4);
  float* gp   = (float*)alloc(64 * 32 * 4);
  float* WfB  = (float*)alloc(2 * 4 * 16 * 32 * 4);
  float* bfB  = (float*)alloc(2 * 4 * 32 * 4);
  unsigned short* qB  = (unsigned short*)alloc((size_t)N * 128 * 2);
  unsigned short* AB  = (unsigned short*)alloc((size_t)N * 128 * 2);
  unsigned int* stats = (unsigned int*)alloc((size_t)N * 256 * 4);  // [N][4][64] uints

  int nb = (N + 1023) / 1024;
  zero_int2<<<(N + 255) / 256, 256, 0, stream>>>(deg, cnt, N);
  hist_kernel<<<(E + 255) / 256, 256, 0, stream>>>(dstp, deg, E);
  scan1_kernel<<<nb, 1024, 0, stream>>>(deg, coff, part, N);
  scan2_kernel<<<1, 64, 0, stream>>>(part, coff, nb, N);
  scan3_kernel<<<nb, 1024, 0, stream>>>(coff, part, N);
  fill_kernel<<<(E + 255) / 256, 256, 0, stream>>>(dstp, coff, cnt, edg, E);
  sort_kernel<<<(N + 255) / 256, 256, 0, stream>>>(coff, edg, N);
  gather_kernel<<<(E + 255) / 256, 256, 0, stream>>>(edg, srcp, ew, srcs, ews, E);
  adl_kernel<<<1, 1024, 0, stream>>>(deg, adl, N);
  node_emb_kernel<<<(N + 7) / 8, 256, 0, stream>>>(x, nodeW, nodeB, h, N);
  fuse_kernel<<<1, 256, 0, stream>>>(edgeW, edgeB, encW, encB, preW, preB, WfB, bfB);

  for (int l = 0; l < 2; l++) {
    prep_kernel<<<(N + 15) / 16, 256, 0, stream>>>(
        h, preW + (size_t)l * 12288, bfB + (size_t)l * 128, qB, AB, N);
    agg_kernel<<<(N + 3) / 4, 256, 0, stream>>>(
        (const unsigned int*)qB, (const unsigned int*)AB, coff, srcs, ews, edg,
        eattr, WfB + (size_t)l * 2048, stats, N);
    post_kernel<<<512, 256, 0, stream>>>(
        h, stats, coff, adl,
        postW + (size_t)l * 13312, postB + (size_t)l * 32,
        linW + (size_t)l * 1024, linB + (size_t)l * 32, pre, N);
    bn_stats_kernel<<<32, 256, 0, stream>>>(pre, bn, N);
    bn_apply_kernel<<<(N * 32 + 255) / 256, 256, 0, stream>>>(pre, bn, bnG + (size_t)l * 32,
                                                              bnB + (size_t)l * 32, h, N);
  }
  pool_kernel<<<64, 256, 0, stream>>>(h, batch, gp, N);
  mlp_kernel<<<1, 256, 0, stream>>>(gp, W1, b1, W2, b2, W3, b3, out);
}